// Round 1
// baseline (5569.905 us; speedup 1.0000x reference)
//
#include <hip/hip_runtime.h>
#include <hip/hip_bf16.h>
#include <math.h>

// AutoregressiveFormulaDecoder: 2-layer GRU decoder, B=8192, T=49 steps, HID=256.
// Round 0: correct baseline. bf16 MFMA GEMMs (weights converted once per call),
// fp32 carry for recurrent h, fused head (hdd in LDS -> logits).

#define BATCH 8192
#define TTOT 50
#define TS 49
#define HID 256
#define N3 768
#define VOCAB 148
#define START_TOK 1

typedef short bf16x8 __attribute__((ext_vector_type(8)));
typedef float f32x4 __attribute__((ext_vector_type(4)));

// ---- workspace layout (bytes) ----
constexpr size_t OFF_H0F  = 0;                       // 8192*256*4
constexpr size_t OFF_H1F  = OFF_H0F + 8388608;
constexpr size_t OFF_H0B  = OFF_H1F + 8388608;       // bf16
constexpr size_t OFF_H1B  = OFF_H0B + 4194304;
constexpr size_t OFF_GI0  = OFF_H1B + 4194304;       // 8192*768*4
constexpr size_t OFF_GH0  = OFF_GI0 + 25165824;
constexpr size_t OFF_GH1  = OFF_GH0 + 25165824;
constexpr size_t OFF_GI1  = OFF_GH1 + 25165824;
constexpr size_t OFF_Y    = OFF_GI1 + 25165824;      // 49*8192*256*2 bf16
constexpr size_t OFF_WI0B = OFF_Y + 205520896;       // 768*256*2
constexpr size_t OFF_WH0B = OFF_WI0B + 393216;
constexpr size_t OFF_WI1B = OFF_WH0B + 393216;
constexpr size_t OFF_WH1B = OFF_WI1B + 393216;
constexpr size_t OFF_W1B  = OFF_WH1B + 393216;       // 256*256*2
constexpr size_t OFF_W2B  = OFF_W1B + 131072;        // 160*256*2 (padded to 160 rows)
constexpr size_t OFF_EMBB = OFF_W2B + 81920;         // 148*256*2

__device__ __forceinline__ short f2b(float f) {
    union { float f; unsigned int u; } v; v.f = f;
    unsigned int u = v.u;
    return (short)((u + 0x7FFFu + ((u >> 16) & 1u)) >> 16);
}

// ---- convert weights (and emb) to bf16 once per call ----
__global__ __launch_bounds__(256) void convert_w(
    const float* __restrict__ Wi0, const float* __restrict__ Wh0,
    const float* __restrict__ Wi1, const float* __restrict__ Wh1,
    const float* __restrict__ W1, const float* __restrict__ W2,
    const float* __restrict__ emb,
    short* __restrict__ Wi0b, short* __restrict__ Wh0b,
    short* __restrict__ Wi1b, short* __restrict__ Wh1b,
    short* __restrict__ W1b, short* __restrict__ W2b, short* __restrict__ embB)
{
    int tid = blockIdx.x * 256 + threadIdx.x;
    const int WSZ = N3 * HID; // 196608
    if (tid < WSZ) { Wi0b[tid] = f2b(Wi0[tid]); return; } tid -= WSZ;
    if (tid < WSZ) { Wh0b[tid] = f2b(Wh0[tid]); return; } tid -= WSZ;
    if (tid < WSZ) { Wi1b[tid] = f2b(Wi1[tid]); return; } tid -= WSZ;
    if (tid < WSZ) { Wh1b[tid] = f2b(Wh1[tid]); return; } tid -= WSZ;
    if (tid < 65536) { W1b[tid] = f2b(W1[tid]); return; } tid -= 65536;
    if (tid < 40960) { // W2 padded to 160 rows, pad = 0
        int row = tid >> 8;
        W2b[tid] = (row < VOCAB) ? f2b(W2[tid]) : (short)0;
        return;
    } tid -= 40960;
    if (tid < 37888) { embB[tid] = f2b(emb[tid]); }
}

// ---- h_init = z @ W_lat.T + b_lat ----
__global__ __launch_bounds__(256) void init_h(
    const float* __restrict__ z, const float* __restrict__ Wl, const float* __restrict__ bl,
    float* __restrict__ h0f, float* __restrict__ h1f,
    short* __restrict__ h0b, short* __restrict__ h1b)
{
    int tid = blockIdx.x * 256 + threadIdx.x;   // b*512 + o
    int b = tid >> 9, o = tid & 511;
    const float* zr = z + b * 32;
    const float* wr = Wl + o * 32;
    float s = bl[o];
    #pragma unroll
    for (int k = 0; k < 32; ++k) s += zr[k] * wr[k];
    if (o < HID) { h0f[b * HID + o] = s; h0b[b * HID + o] = f2b(s); }
    else         { h1f[b * HID + o - HID] = s; h1b[b * HID + o - HID] = f2b(s); }
}

// ---- recurrent GEMM: out[M=8192, N=768] = A[M,256] @ W[768,256].T (bf16 MFMA) ----
// mode 0: blockIdx.z selects {gi0 (emb gather), gh0, gh1}; mode 1: single GEMM (gi1)
__global__ __launch_bounds__(256) void gemm_step(
    const short* __restrict__ embB, const int* __restrict__ toks, int t, int mode,
    const short* __restrict__ Ah0, const short* __restrict__ Ah1,
    const short* __restrict__ Wi0, const short* __restrict__ Wh0, const short* __restrict__ Wh1,
    float* __restrict__ gi0, float* __restrict__ gh0, float* __restrict__ gh1)
{
    int wave = threadIdx.x >> 6;
    int lane = threadIdx.x & 63;
    int quad = lane >> 4;
    int l15  = lane & 15;

    const short* A = nullptr; const short* W; float* out; bool gather = false;
    if (mode == 1) { A = Ah0; W = Wi0; out = gi0; }
    else if (blockIdx.z == 0) { gather = true; W = Wi0; out = gi0; }
    else if (blockIdx.z == 1) { A = Ah0; W = Wh0; out = gh0; }
    else { A = Ah1; W = Wh1; out = gh1; }

    int mbase = blockIdx.y * 128 + wave * 32;
    int nbase = blockIdx.x * 64;

    const short* ap[2];
    #pragma unroll
    for (int i = 0; i < 2; ++i) {
        int row = mbase + i * 16 + l15;
        if (gather) {
            int tok = (t == 0) ? START_TOK : toks[row * TTOT + t];
            ap[i] = embB + tok * HID;
        } else ap[i] = A + row * HID;
    }
    const short* wp[4];
    #pragma unroll
    for (int j = 0; j < 4; ++j) wp[j] = W + (nbase + j * 16 + l15) * HID;

    f32x4 acc[2][4] = {};
    #pragma unroll
    for (int k0 = 0; k0 < HID; k0 += 32) {
        bf16x8 a[2], bfr[4];
        #pragma unroll
        for (int i = 0; i < 2; ++i) a[i] = *(const bf16x8*)(ap[i] + k0 + quad * 8);
        #pragma unroll
        for (int j = 0; j < 4; ++j) bfr[j] = *(const bf16x8*)(wp[j] + k0 + quad * 8);
        #pragma unroll
        for (int i = 0; i < 2; ++i)
            #pragma unroll
            for (int j = 0; j < 4; ++j)
                acc[i][j] = __builtin_amdgcn_mfma_f32_16x16x32_bf16(a[i], bfr[j], acc[i][j], 0, 0, 0);
    }
    #pragma unroll
    for (int i = 0; i < 2; ++i)
        #pragma unroll
        for (int j = 0; j < 4; ++j)
            #pragma unroll
            for (int r = 0; r < 4; ++r) {
                int row = mbase + i * 16 + quad * 4 + r;
                int col = nbase + j * 16 + l15;
                out[row * N3 + col] = acc[i][j][r];
            }
}

// ---- GRU elementwise combine (fp32 carry) ----
__global__ __launch_bounds__(256) void gru_elem(
    const float* __restrict__ gi, const float* __restrict__ gh,
    const float* __restrict__ b_ih, const float* __restrict__ b_hh,
    float* __restrict__ hf, short* __restrict__ hb, short* __restrict__ yout)
{
    int tid = blockIdx.x * 256 + threadIdx.x;
    int b = tid >> 8, i = tid & 255;
    const float* gir = gi + b * N3;
    const float* ghr = gh + b * N3;
    float xr = gir[i]       + b_ih[i]       + ghr[i]       + b_hh[i];
    float xz = gir[i + 256] + b_ih[i + 256] + ghr[i + 256] + b_hh[i + 256];
    float in_ = gir[i + 512] + b_ih[i + 512];
    float hnn = ghr[i + 512] + b_hh[i + 512];
    float r  = 1.f / (1.f + expf(-xr));
    float zg = 1.f / (1.f + expf(-xz));
    float n  = tanhf(in_ + r * hnn);
    float h  = (1.f - zg) * n + zg * hf[tid];
    hf[tid] = h;
    short hb16 = f2b(h);
    hb[tid] = hb16;
    if (yout) yout[tid] = hb16;
}

// ---- fused head: hdd = relu(Y@W1.T+b1) in LDS, logits = hdd@W2.T+b2 -> d_out ----
__global__ __launch_bounds__(256) void head_kernel(
    const short* __restrict__ Y, const short* __restrict__ W1b, const float* __restrict__ b1,
    const short* __restrict__ W2b, const float* __restrict__ b2, float* __restrict__ out)
{
    __shared__ short hddL[64 * 256];
    int wave = threadIdx.x >> 6;
    int lane = threadIdx.x & 63;
    int quad = lane >> 4;
    int l15  = lane & 15;
    int rbase = blockIdx.x * 64;

    { // stage A: hdd tile 64x256, wave w owns n-range [w*64, w*64+64)
        int nb = wave * 64;
        const short* ap[4]; const short* wp[4];
        #pragma unroll
        for (int i = 0; i < 4; ++i) ap[i] = Y + (size_t)(rbase + i * 16 + l15) * HID;
        #pragma unroll
        for (int j = 0; j < 4; ++j) wp[j] = W1b + (nb + j * 16 + l15) * HID;
        f32x4 acc[4][4] = {};
        #pragma unroll
        for (int k0 = 0; k0 < HID; k0 += 32) {
            bf16x8 a[4], bfr[4];
            #pragma unroll
            for (int i = 0; i < 4; ++i) a[i] = *(const bf16x8*)(ap[i] + k0 + quad * 8);
            #pragma unroll
            for (int j = 0; j < 4; ++j) bfr[j] = *(const bf16x8*)(wp[j] + k0 + quad * 8);
            #pragma unroll
            for (int i = 0; i < 4; ++i)
                #pragma unroll
                for (int j = 0; j < 4; ++j)
                    acc[i][j] = __builtin_amdgcn_mfma_f32_16x16x32_bf16(a[i], bfr[j], acc[i][j], 0, 0, 0);
        }
        #pragma unroll
        for (int i = 0; i < 4; ++i)
            #pragma unroll
            for (int j = 0; j < 4; ++j)
                #pragma unroll
                for (int r = 0; r < 4; ++r) {
                    int rl = i * 16 + quad * 4 + r;
                    int c  = nb + j * 16 + l15;
                    float v = acc[i][j][r] + b1[c];
                    hddL[rl * 256 + c] = f2b(fmaxf(v, 0.f));
                }
    }
    __syncthreads();
    // stage B: logits 64x148 (10 n-tiles of 16, padded W2 rows are zero)
    for (int nt = wave; nt < 10; nt += 4) {
        f32x4 acc[4] = {};
        const short* wp = W2b + (nt * 16 + l15) * HID;
        #pragma unroll
        for (int k0 = 0; k0 < HID; k0 += 32) {
            bf16x8 bfr = *(const bf16x8*)(wp + k0 + quad * 8);
            #pragma unroll
            for (int i = 0; i < 4; ++i) {
                bf16x8 a = *(const bf16x8*)(&hddL[(i * 16 + l15) * 256 + k0 + quad * 8]);
                acc[i] = __builtin_amdgcn_mfma_f32_16x16x32_bf16(a, bfr, acc[i], 0, 0, 0);
            }
        }
        int col = nt * 16 + l15;
        if (col < VOCAB) {
            #pragma unroll
            for (int i = 0; i < 4; ++i)
                #pragma unroll
                for (int r = 0; r < 4; ++r) {
                    int rl = i * 16 + quad * 4 + r;
                    int gr = rbase + rl;
                    int tt = gr >> 13;        // row = t*8192 + b
                    int bb = gr & 8191;
                    out[((size_t)bb * TS + tt) * VOCAB + col] = acc[i][r] + b2[col];
                }
        }
    }
}

// ---- generated = target_tokens[:,1:] as float ----
__global__ __launch_bounds__(256) void gen_copy(const int* __restrict__ toks, float* __restrict__ out2)
{
    int tid = blockIdx.x * 256 + threadIdx.x;
    if (tid < BATCH * TS) {
        int b = tid / TS, j = tid - b * TS;
        out2[tid] = (float)toks[b * TTOT + j + 1];
    }
}

extern "C" void kernel_launch(void* const* d_in, const int* in_sizes, int n_in,
                              void* d_out, int out_size, void* d_ws, size_t ws_size,
                              hipStream_t stream) {
    const float* z     = (const float*)d_in[0];
    const int*   toks  = (const int*)d_in[1];
    const float* emb   = (const float*)d_in[2];
    const float* W_lat = (const float*)d_in[3];
    const float* b_lat = (const float*)d_in[4];
    const float* W_ih0 = (const float*)d_in[5];
    const float* W_hh0 = (const float*)d_in[6];
    const float* b_ih0 = (const float*)d_in[7];
    const float* b_hh0 = (const float*)d_in[8];
    const float* W_ih1 = (const float*)d_in[9];
    const float* W_hh1 = (const float*)d_in[10];
    const float* b_ih1 = (const float*)d_in[11];
    const float* b_hh1 = (const float*)d_in[12];
    const float* W1    = (const float*)d_in[13];
    const float* b1    = (const float*)d_in[14];
    const float* W2    = (const float*)d_in[15];
    const float* b2    = (const float*)d_in[16];

    char* w = (char*)d_ws;
    float* h0f = (float*)(w + OFF_H0F);
    float* h1f = (float*)(w + OFF_H1F);
    short* h0b = (short*)(w + OFF_H0B);
    short* h1b = (short*)(w + OFF_H1B);
    float* gi0 = (float*)(w + OFF_GI0);
    float* gh0 = (float*)(w + OFF_GH0);
    float* gh1 = (float*)(w + OFF_GH1);
    float* gi1 = (float*)(w + OFF_GI1);
    short* Yb  = (short*)(w + OFF_Y);
    short* Wi0b = (short*)(w + OFF_WI0B);
    short* Wh0b = (short*)(w + OFF_WH0B);
    short* Wi1b = (short*)(w + OFF_WI1B);
    short* Wh1b = (short*)(w + OFF_WH1B);
    short* W1b  = (short*)(w + OFF_W1B);
    short* W2b  = (short*)(w + OFF_W2B);
    short* embB = (short*)(w + OFF_EMBB);

    float* out_logits = (float*)d_out;
    float* out_gen    = out_logits + (size_t)BATCH * TS * VOCAB;

    convert_w<<<3636, 256, 0, stream>>>(W_ih0, W_hh0, W_ih1, W_hh1, W1, W2, emb,
                                        Wi0b, Wh0b, Wi1b, Wh1b, W1b, W2b, embB);
    init_h<<<(BATCH * 512) / 256, 256, 0, stream>>>(z, W_lat, b_lat, h0f, h1f, h0b, h1b);
    gen_copy<<<(BATCH * TS + 255) / 256, 256, 0, stream>>>(toks, out_gen);

    for (int t = 0; t < TS; ++t) {
        // stage 1: gi0 (emb gather), gh0 = h0@W_hh0.T, gh1 = h1@W_hh1.T
        gemm_step<<<dim3(12, 64, 3), 256, 0, stream>>>(embB, toks, t, 0, h0b, h1b,
                                                       Wi0b, Wh0b, Wh1b, gi0, gh0, gh1);
        // layer-0 combine -> h0
        gru_elem<<<(BATCH * HID) / 256, 256, 0, stream>>>(gi0, gh0, b_ih0, b_hh0,
                                                          h0f, h0b, (short*)nullptr);
        // stage 2: gi1 = h0n @ W_ih1.T
        gemm_step<<<dim3(12, 64, 1), 256, 0, stream>>>(embB, toks, t, 1, h0b, (const short*)nullptr,
                                                       Wi1b, (const short*)nullptr, (const short*)nullptr,
                                                       gi1, (float*)nullptr, (float*)nullptr);
        // layer-1 combine -> h1, Y[t]
        gru_elem<<<(BATCH * HID) / 256, 256, 0, stream>>>(gi1, gh1, b_ih1, b_hh1,
                                                          h1f, h1b, Yb + (size_t)t * BATCH * HID);
    }

    head_kernel<<<(BATCH * TS) / 64, 256, 0, stream>>>(Yb, W1b, b1, W2b, b2, out_logits);
}

// Round 2
// 2981.920 us; speedup vs baseline: 1.8679x; 1.8679x over previous
//
#include <hip/hip_runtime.h>
#include <hip/hip_bf16.h>
#include <math.h>

// Round 1: persistent GRU recurrence (1 launch, batch-sliced blocks, h in regs,
// weights streamed from L2), gi0 via precomputed fp32 token table, fixed head.

#define BATCH 8192
#define TTOT 50
#define TS 49
#define HID 256
#define N3 768
#define VOCAB 148
#define START_TOK 1
#define HPAD 264   // LDS leading dim for 256-col bf16 tiles (2-way conflicts only)

typedef short bf16x8 __attribute__((ext_vector_type(8)));
typedef float f32x4 __attribute__((ext_vector_type(4)));

// ---- workspace layout (bytes) ----
constexpr size_t OFF_Y    = 0;                        // 49*8192*256*2
constexpr size_t OFF_WH0B = OFF_Y + 205520896;        // 768*256*2
constexpr size_t OFF_WI1B = OFF_WH0B + 393216;
constexpr size_t OFF_WH1B = OFF_WI1B + 393216;
constexpr size_t OFF_W1B  = OFF_WH1B + 393216;        // 256*256*2
constexpr size_t OFF_W2B  = OFF_W1B + 131072;         // 160*256*2 (padded rows)
constexpr size_t OFF_TAB  = OFF_W2B + 81920;          // 148*768*4 fp32
constexpr size_t OFF_H0F  = OFF_TAB + 454656;         // 8192*256*4
constexpr size_t OFF_H1F  = OFF_H0F + 8388608;

__device__ __forceinline__ short f2b(float f) {
    union { float f; unsigned int u; } v; v.f = f;
    unsigned int u = v.u;
    return (short)((u + 0x7FFFu + ((u >> 16) & 1u)) >> 16);
}
__device__ __forceinline__ float sigm(float x) {
    x = fminf(fmaxf(x, -30.f), 30.f);
    return 1.f / (1.f + __expf(-x));
}
__device__ __forceinline__ float tanh_(float x) {
    x = fminf(fmaxf(x, -15.f), 15.f);
    float e = __expf(-2.f * x);
    return (1.f - e) / (1.f + e);
}

// ---- bf16 weight conversion ----
__global__ __launch_bounds__(256) void convert_w(
    const float* __restrict__ Wh0, const float* __restrict__ Wi1, const float* __restrict__ Wh1,
    const float* __restrict__ W1, const float* __restrict__ W2,
    short* __restrict__ Wh0b, short* __restrict__ Wi1b, short* __restrict__ Wh1b,
    short* __restrict__ W1b, short* __restrict__ W2b)
{
    int tid = blockIdx.x * 256 + threadIdx.x;
    const int WSZ = N3 * HID;
    if (tid < WSZ) { Wh0b[tid] = f2b(Wh0[tid]); return; } tid -= WSZ;
    if (tid < WSZ) { Wi1b[tid] = f2b(Wi1[tid]); return; } tid -= WSZ;
    if (tid < WSZ) { Wh1b[tid] = f2b(Wh1[tid]); return; } tid -= WSZ;
    if (tid < 65536) { W1b[tid] = f2b(W1[tid]); return; } tid -= 65536;
    if (tid < 40960) {
        int row = tid >> 8;
        W2b[tid] = (row < VOCAB) ? f2b(W2[tid]) : (short)0;
    }
}

// ---- token table: tab[v][o] = b_ih0[o] + emb[v,:]·W_ih0[o,:]  (fp32) ----
__global__ __launch_bounds__(256) void build_tab(
    const float* __restrict__ emb, const float* __restrict__ Wih0,
    const float* __restrict__ bih0, float* __restrict__ tab)
{
    int o = blockIdx.x * 256 + threadIdx.x;
    if (o >= VOCAB * N3) return;
    int v = o / N3, c = o - v * N3;
    const float* er = emb + v * HID;
    const float* wr = Wih0 + c * HID;
    float s = bih0[c];
    #pragma unroll 8
    for (int k = 0; k < HID; ++k) s += er[k] * wr[k];
    tab[o] = s;
}

// ---- h_init = z @ W_lat.T + b_lat (fp32) ----
__global__ __launch_bounds__(256) void init_h(
    const float* __restrict__ z, const float* __restrict__ Wl, const float* __restrict__ bl,
    float* __restrict__ h0f, float* __restrict__ h1f)
{
    int tid = blockIdx.x * 256 + threadIdx.x;   // b*512 + o
    int b = tid >> 9, o = tid & 511;
    const float* zr = z + b * 32;
    const float* wr = Wl + o * 32;
    float s = bl[o];
    #pragma unroll
    for (int k = 0; k < 32; ++k) s += zr[k] * wr[k];
    if (o < HID) h0f[b * HID + o] = s;
    else         h1f[b * HID + o - HID] = s;
}

// ---- persistent recurrence: block owns 64 batch rows for all 49 steps ----
__global__ __launch_bounds__(512, 2) void gru_persistent(
    const int* __restrict__ toks, const float* __restrict__ tab,
    const short* __restrict__ Wh0, const short* __restrict__ Wi1, const short* __restrict__ Wh1,
    const float* __restrict__ bhh0, const float* __restrict__ bih1, const float* __restrict__ bhh1,
    const float* __restrict__ h0f, const float* __restrict__ h1f,
    short* __restrict__ Yb)
{
    __shared__ short h0L[64 * HPAD];
    __shared__ short h1L[64 * HPAD];
    __shared__ int tokL[64 * TTOT];

    const int tid = threadIdx.x;
    const int wave = tid >> 6, lane = tid & 63, quad = lane >> 4, l15 = lane & 15;
    const int rowbase = blockIdx.x * 64;

    // --- stage LDS h (bf16) + tokens, h in fp32 regs ---
    for (int idx = tid; idx < 2048; idx += 512) {        // 64 rows * 32 chunks of 8
        int row = idx >> 5, col = (idx & 31) * 8;
        const float* s0 = h0f + (size_t)(rowbase + row) * HID + col;
        const float* s1 = h1f + (size_t)(rowbase + row) * HID + col;
        short t0[8], t1[8];
        #pragma unroll
        for (int j = 0; j < 8; ++j) { t0[j] = f2b(s0[j]); t1[j] = f2b(s1[j]); }
        *(bf16x8*)&h0L[row * HPAD + col] = *(bf16x8*)t0;
        *(bf16x8*)&h1L[row * HPAD + col] = *(bf16x8*)t1;
    }
    for (int idx = tid; idx < 64 * TTOT; idx += 512) {
        int row = idx / TTOT, tt = idx - row * TTOT;
        tokL[idx] = (tt == 0) ? START_TOK : toks[(size_t)(rowbase + row) * TTOT + tt];
    }

    float h0r[4][2][4], h1r[4][2][4];
    #pragma unroll
    for (int i = 0; i < 4; ++i)
        #pragma unroll
        for (int c = 0; c < 2; ++c) {
            int col = wave * 32 + c * 16 + l15;
            #pragma unroll
            for (int r_ = 0; r_ < 4; ++r_) {
                int row = rowbase + 16 * i + quad * 4 + r_;
                h0r[i][c][r_] = h0f[(size_t)row * HID + col];
                h1r[i][c][r_] = h1f[(size_t)row * HID + col];
            }
        }
    __syncthreads();

    // column bases for this wave's gate-triplet slice (j = gate*2 + half)
    int cb[6];
    #pragma unroll
    for (int g = 0; g < 3; ++g)
        #pragma unroll
        for (int c = 0; c < 2; ++c) cb[g * 2 + c] = g * 256 + wave * 32 + c * 16 + l15;

    for (int t = 0; t < TS; ++t) {
        // ---- kloop gh0 = h0 @ Wh0.T (full r,z,n slice) ----
        f32x4 acc0[4][6] = {};
        #pragma unroll 2
        for (int k0 = 0; k0 < HID; k0 += 32) {
            bf16x8 a[4];
            #pragma unroll
            for (int i = 0; i < 4; ++i)
                a[i] = *(const bf16x8*)&h0L[(16 * i + l15) * HPAD + k0 + quad * 8];
            #pragma unroll
            for (int j = 0; j < 6; ++j) {
                bf16x8 b = *(const bf16x8*)(Wh0 + (size_t)cb[j] * HID + k0 + quad * 8);
                #pragma unroll
                for (int i = 0; i < 4; ++i)
                    acc0[i][j] = __builtin_amdgcn_mfma_f32_16x16x32_bf16(a[i], b, acc0[i][j], 0, 0, 0);
            }
        }
        // ---- layer-0 gates: gi0 from token table ----
        #pragma unroll
        for (int c = 0; c < 2; ++c) {
            int col = wave * 32 + c * 16 + l15;
            float br = bhh0[col], bz = bhh0[256 + col], bn = bhh0[512 + col];
            #pragma unroll
            for (int i = 0; i < 4; ++i)
                #pragma unroll
                for (int r_ = 0; r_ < 4; ++r_) {
                    int rl = 16 * i + quad * 4 + r_;
                    const float* tp = tab + (size_t)tokL[rl * TTOT + t] * N3 + col;
                    float r  = sigm(acc0[i][c][r_] + br + tp[0]);
                    float z  = sigm(acc0[i][2 + c][r_] + bz + tp[256]);
                    float n  = tanh_(tp[512] + r * (acc0[i][4 + c][r_] + bn));
                    h0r[i][c][r_] = (1.f - z) * n + z * h0r[i][c][r_];
                }
        }
        __syncthreads();   // all waves done reading h0L
        #pragma unroll
        for (int c = 0; c < 2; ++c) {
            int col = wave * 32 + c * 16 + l15;
            #pragma unroll
            for (int i = 0; i < 4; ++i)
                #pragma unroll
                for (int r_ = 0; r_ < 4; ++r_)
                    h0L[(16 * i + quad * 4 + r_) * HPAD + col] = f2b(h0r[i][c][r_]);
        }
        __syncthreads();   // h0n visible to all

        // ---- kloop gh1 = h1 @ Wh1.T  (rz into shared acc, n separate) ----
        f32x4 accrz[4][4] = {}, acchn[4][2] = {}, accgn[4][2] = {};
        #pragma unroll 2
        for (int k0 = 0; k0 < HID; k0 += 32) {
            bf16x8 a[4];
            #pragma unroll
            for (int i = 0; i < 4; ++i)
                a[i] = *(const bf16x8*)&h1L[(16 * i + l15) * HPAD + k0 + quad * 8];
            #pragma unroll
            for (int j = 0; j < 6; ++j) {
                bf16x8 b = *(const bf16x8*)(Wh1 + (size_t)cb[j] * HID + k0 + quad * 8);
                #pragma unroll
                for (int i = 0; i < 4; ++i) {
                    if (j < 4) accrz[i][j] = __builtin_amdgcn_mfma_f32_16x16x32_bf16(a[i], b, accrz[i][j], 0, 0, 0);
                    else       acchn[i][j - 4] = __builtin_amdgcn_mfma_f32_16x16x32_bf16(a[i], b, acchn[i][j - 4], 0, 0, 0);
                }
            }
        }
        // ---- kloop gi1 = h0n @ Wi1.T (rz accumulates on top of gh1 rz) ----
        #pragma unroll 2
        for (int k0 = 0; k0 < HID; k0 += 32) {
            bf16x8 a[4];
            #pragma unroll
            for (int i = 0; i < 4; ++i)
                a[i] = *(const bf16x8*)&h0L[(16 * i + l15) * HPAD + k0 + quad * 8];
            #pragma unroll
            for (int j = 0; j < 6; ++j) {
                bf16x8 b = *(const bf16x8*)(Wi1 + (size_t)cb[j] * HID + k0 + quad * 8);
                #pragma unroll
                for (int i = 0; i < 4; ++i) {
                    if (j < 4) accrz[i][j] = __builtin_amdgcn_mfma_f32_16x16x32_bf16(a[i], b, accrz[i][j], 0, 0, 0);
                    else       accgn[i][j - 4] = __builtin_amdgcn_mfma_f32_16x16x32_bf16(a[i], b, accgn[i][j - 4], 0, 0, 0);
                }
            }
        }
        // ---- layer-1 gates ----
        #pragma unroll
        for (int c = 0; c < 2; ++c) {
            int col = wave * 32 + c * 16 + l15;
            float brr = bih1[col] + bhh1[col];
            float brz = bih1[256 + col] + bhh1[256 + col];
            float bni = bih1[512 + col], bnh = bhh1[512 + col];
            #pragma unroll
            for (int i = 0; i < 4; ++i)
                #pragma unroll
                for (int r_ = 0; r_ < 4; ++r_) {
                    float r = sigm(accrz[i][c][r_] + brr);
                    float z = sigm(accrz[i][2 + c][r_] + brz);
                    float n = tanh_(accgn[i][c][r_] + bni + r * (acchn[i][c][r_] + bnh));
                    h1r[i][c][r_] = (1.f - z) * n + z * h1r[i][c][r_];
                }
        }
        __syncthreads();   // all waves done reading h1L
        #pragma unroll
        for (int c = 0; c < 2; ++c) {
            int col = wave * 32 + c * 16 + l15;
            #pragma unroll
            for (int i = 0; i < 4; ++i)
                #pragma unroll
                for (int r_ = 0; r_ < 4; ++r_)
                    h1L[(16 * i + quad * 4 + r_) * HPAD + col] = f2b(h1r[i][c][r_]);
        }
        __syncthreads();   // h1n visible

        // ---- coalesced Y[t] write from h1L ----
        short* ybt = Yb + (size_t)t * BATCH * HID;
        for (int idx = tid; idx < 2048; idx += 512) {
            int row = idx >> 5, col = (idx & 31) * 8;
            *(bf16x8*)&ybt[(size_t)(rowbase + row) * HID + col] =
                *(const bf16x8*)&h1L[row * HPAD + col];
        }
        // no barrier needed: next touch of h0L/h1L reads happen after next step's barriers
        __syncthreads();
    }
}

// ---- fused head: hdd = relu(Y@W1.T+b1) in LDS, logits = hdd@W2.T+b2 ----
__global__ __launch_bounds__(256) void head_kernel(
    const short* __restrict__ Y, const short* __restrict__ W1b, const float* __restrict__ b1,
    const short* __restrict__ W2b, const float* __restrict__ b2, float* __restrict__ out)
{
    __shared__ short hddL[64 * HPAD];
    int wave = threadIdx.x >> 6;
    int lane = threadIdx.x & 63;
    int quad = lane >> 4;
    int l15  = lane & 15;
    int rbase = blockIdx.x * 64;

    { // stage A: hdd tile 64x256, wave w owns n-range [w*64, w*64+64)
        int nb = wave * 64;
        const short* ap[4]; const short* wp[4];
        #pragma unroll
        for (int i = 0; i < 4; ++i) ap[i] = Y + (size_t)(rbase + i * 16 + l15) * HID;
        #pragma unroll
        for (int j = 0; j < 4; ++j) wp[j] = W1b + (size_t)(nb + j * 16 + l15) * HID;
        f32x4 acc[4][4] = {};
        #pragma unroll 2
        for (int k0 = 0; k0 < HID; k0 += 32) {
            bf16x8 a[4], bfr[4];
            #pragma unroll
            for (int i = 0; i < 4; ++i) a[i] = *(const bf16x8*)(ap[i] + k0 + quad * 8);
            #pragma unroll
            for (int j = 0; j < 4; ++j) bfr[j] = *(const bf16x8*)(wp[j] + k0 + quad * 8);
            #pragma unroll
            for (int i = 0; i < 4; ++i)
                #pragma unroll
                for (int j = 0; j < 4; ++j)
                    acc[i][j] = __builtin_amdgcn_mfma_f32_16x16x32_bf16(a[i], bfr[j], acc[i][j], 0, 0, 0);
        }
        #pragma unroll
        for (int i = 0; i < 4; ++i)
            #pragma unroll
            for (int j = 0; j < 4; ++j)
                #pragma unroll
                for (int r = 0; r < 4; ++r) {
                    int rl = i * 16 + quad * 4 + r;
                    int c  = nb + j * 16 + l15;
                    float v = acc[i][j][r] + b1[c];
                    hddL[rl * HPAD + c] = f2b(fmaxf(v, 0.f));
                }
    }
    __syncthreads();
    // stage B: 20 subtiles (10 col-tiles x 2 row-halves) / 4 waves = 5 each
    for (int s = wave * 5; s < wave * 5 + 5; ++s) {
        int ct = s >> 1, rh = s & 1;
        f32x4 acc2[2] = {};
        const short* wp = W2b + (size_t)(ct * 16 + l15) * HID;
        #pragma unroll 2
        for (int k0 = 0; k0 < HID; k0 += 32) {
            bf16x8 bfr = *(const bf16x8*)(wp + k0 + quad * 8);
            #pragma unroll
            for (int it = 0; it < 2; ++it) {
                bf16x8 a = *(const bf16x8*)&hddL[(rh * 32 + it * 16 + l15) * HPAD + k0 + quad * 8];
                acc2[it] = __builtin_amdgcn_mfma_f32_16x16x32_bf16(a, bfr, acc2[it], 0, 0, 0);
            }
        }
        int col = ct * 16 + l15;
        if (col < VOCAB) {
            #pragma unroll
            for (int it = 0; it < 2; ++it)
                #pragma unroll
                for (int r = 0; r < 4; ++r) {
                    int rl = rh * 32 + it * 16 + quad * 4 + r;
                    int gr = rbase + rl;
                    int tt = gr >> 13;        // row = t*8192 + b
                    int bb = gr & 8191;
                    out[((size_t)bb * TS + tt) * VOCAB + col] = acc2[it][r] + b2[col];
                }
        }
    }
}

// ---- generated = target_tokens[:,1:] as float ----
__global__ __launch_bounds__(256) void gen_copy(const int* __restrict__ toks, float* __restrict__ out2)
{
    int tid = blockIdx.x * 256 + threadIdx.x;
    if (tid < BATCH * TS) {
        int b = tid / TS, j = tid - b * TS;
        out2[tid] = (float)toks[b * TTOT + j + 1];
    }
}

extern "C" void kernel_launch(void* const* d_in, const int* in_sizes, int n_in,
                              void* d_out, int out_size, void* d_ws, size_t ws_size,
                              hipStream_t stream) {
    const float* z     = (const float*)d_in[0];
    const int*   toks  = (const int*)d_in[1];
    const float* emb   = (const float*)d_in[2];
    const float* W_lat = (const float*)d_in[3];
    const float* b_lat = (const float*)d_in[4];
    const float* W_ih0 = (const float*)d_in[5];
    const float* W_hh0 = (const float*)d_in[6];
    const float* b_ih0 = (const float*)d_in[7];
    const float* b_hh0 = (const float*)d_in[8];
    const float* W_ih1 = (const float*)d_in[9];
    const float* W_hh1 = (const float*)d_in[10];
    const float* b_ih1 = (const float*)d_in[11];
    const float* b_hh1 = (const float*)d_in[12];
    const float* W1    = (const float*)d_in[13];
    const float* b1    = (const float*)d_in[14];
    const float* W2    = (const float*)d_in[15];
    const float* b2    = (const float*)d_in[16];

    char* w = (char*)d_ws;
    short* Yb   = (short*)(w + OFF_Y);
    short* Wh0b = (short*)(w + OFF_WH0B);
    short* Wi1b = (short*)(w + OFF_WI1B);
    short* Wh1b = (short*)(w + OFF_WH1B);
    short* W1b  = (short*)(w + OFF_W1B);
    short* W2b  = (short*)(w + OFF_W2B);
    float* tab  = (float*)(w + OFF_TAB);
    float* h0f  = (float*)(w + OFF_H0F);
    float* h1f  = (float*)(w + OFF_H1F);

    float* out_logits = (float*)d_out;
    float* out_gen    = out_logits + (size_t)BATCH * TS * VOCAB;

    convert_w<<<2720, 256, 0, stream>>>(W_hh0, W_ih1, W_hh1, W1, W2,
                                        Wh0b, Wi1b, Wh1b, W1b, W2b);
    build_tab<<<(VOCAB * N3 + 255) / 256, 256, 0, stream>>>(emb, W_ih0, b_ih0, tab);
    init_h<<<(BATCH * 512) / 256, 256, 0, stream>>>(z, W_lat, b_lat, h0f, h1f);
    gen_copy<<<(BATCH * TS + 255) / 256, 256, 0, stream>>>(toks, out_gen);

    gru_persistent<<<128, 512, 0, stream>>>(toks, tab, Wh0b, Wi1b, Wh1b,
                                            b_hh0, b_ih1, b_hh1, h0f, h1f, Yb);

    head_kernel<<<(BATCH * TS) / 64, 256, 0, stream>>>(Yb, W1b, b1, W2b, b2, out_logits);
}

// Round 3
// 1437.671 us; speedup vs baseline: 3.8743x; 2.0741x over previous
//
#include <hip/hip_runtime.h>
#include <hip/hip_bf16.h>
#include <math.h>

// Round 2: coalesced fragment-ordered ("swizzled") weights + Y, 256 blocks x 32 rows,
// merged gh0+gh1 kloop. Weight pack: P[ntile][kc][lane][8] so each wave load is one
// contiguous 1KB transaction instead of 16 scattered cache lines.

#define BATCH 8192
#define TTOT 50
#define TS 49
#define HID 256
#define N3 768
#define VOCAB 148
#define START_TOK 1
#define HPAD 264

typedef short bf16x8 __attribute__((ext_vector_type(8)));
typedef float f32x4 __attribute__((ext_vector_type(4)));

// ---- workspace layout (bytes) ----
constexpr size_t OFF_Y    = 0;                        // 49*8192*256*2 (packed)
constexpr size_t OFF_WH0B = OFF_Y + 205520896;        // 768*256*2 packed
constexpr size_t OFF_WI1B = OFF_WH0B + 393216;
constexpr size_t OFF_WH1B = OFF_WI1B + 393216;
constexpr size_t OFF_W1B  = OFF_WH1B + 393216;        // 256*256*2 packed
constexpr size_t OFF_W2B  = OFF_W1B + 131072;         // 160*256*2 packed (rows >=148 zero)
constexpr size_t OFF_TAB  = OFF_W2B + 81920;          // 148*768*4 fp32
constexpr size_t OFF_H0F  = OFF_TAB + 454656;         // 8192*256*4
constexpr size_t OFF_H1F  = OFF_H0F + 8388608;

__device__ __forceinline__ short f2b(float f) {
    union { float f; unsigned int u; } v; v.f = f;
    unsigned int u = v.u;
    return (short)((u + 0x7FFFu + ((u >> 16) & 1u)) >> 16);
}
__device__ __forceinline__ float sigm(float x) {
    x = fminf(fmaxf(x, -30.f), 30.f);
    return 1.f / (1.f + __expf(-x));
}
__device__ __forceinline__ float tanh_(float x) {
    x = fminf(fmaxf(x, -15.f), 15.f);
    float e = __expf(-2.f * x);
    return (1.f - e) / (1.f + e);
}

// ---- convert + swizzle weights into fragment order P[nt][kc][lane][8] ----
// element n of a segment: e=n&7, lane=(n>>3)&63, kc=(n>>9)&7, nt=n>>12
// src = W[(nt*16 + (lane&15))*256 + kc*32 + (lane>>4)*8 + e]
__global__ __launch_bounds__(256) void convert_w(
    const float* __restrict__ Wh0, const float* __restrict__ Wi1, const float* __restrict__ Wh1,
    const float* __restrict__ W1, const float* __restrict__ W2,
    short* __restrict__ Wh0b, short* __restrict__ Wi1b, short* __restrict__ Wh1b,
    short* __restrict__ W1b, short* __restrict__ W2b)
{
    int tid = blockIdx.x * 256 + threadIdx.x;
    const int WSZ = N3 * HID; // 196608
    const float* S; short* D; int n; bool pad148 = false;
    if (tid < WSZ) { S = Wh0; D = Wh0b; n = tid; }
    else if (tid < 2 * WSZ) { S = Wi1; D = Wi1b; n = tid - WSZ; }
    else if (tid < 3 * WSZ) { S = Wh1; D = Wh1b; n = tid - 2 * WSZ; }
    else if (tid < 3 * WSZ + 65536) { S = W1; D = W1b; n = tid - 3 * WSZ; }
    else if (tid < 3 * WSZ + 65536 + 40960) { S = W2; D = W2b; n = tid - 3 * WSZ - 65536; pad148 = true; }
    else return;
    int e = n & 7, lane = (n >> 3) & 63, kc = (n >> 9) & 7, nt = n >> 12;
    int row = nt * 16 + (lane & 15);
    int k = kc * 32 + (lane >> 4) * 8 + e;
    float v = (pad148 && row >= VOCAB) ? 0.f : S[row * HID + k];
    D[n] = f2b(v);
}

// ---- token table: tab[v][o] = b_ih0[o] + emb[v,:]·W_ih0[o,:]  (fp32) ----
__global__ __launch_bounds__(256) void build_tab(
    const float* __restrict__ emb, const float* __restrict__ Wih0,
    const float* __restrict__ bih0, float* __restrict__ tab)
{
    int o = blockIdx.x * 256 + threadIdx.x;
    if (o >= VOCAB * N3) return;
    int v = o / N3, c = o - v * N3;
    const float* er = emb + v * HID;
    const float* wr = Wih0 + c * HID;
    float s = bih0[c];
    #pragma unroll 8
    for (int k = 0; k < HID; ++k) s += er[k] * wr[k];
    tab[o] = s;
}

// ---- h_init = z @ W_lat.T + b_lat (fp32) ----
__global__ __launch_bounds__(256) void init_h(
    const float* __restrict__ z, const float* __restrict__ Wl, const float* __restrict__ bl,
    float* __restrict__ h0f, float* __restrict__ h1f)
{
    int tid = blockIdx.x * 256 + threadIdx.x;   // b*512 + o
    int b = tid >> 9, o = tid & 511;
    const float* zr = z + b * 32;
    const float* wr = Wl + o * 32;
    float s = bl[o];
    #pragma unroll
    for (int k = 0; k < 32; ++k) s += zr[k] * wr[k];
    if (o < HID) h0f[b * HID + o] = s;
    else         h1f[b * HID + o - HID] = s;
}

// ---- persistent recurrence: 256 blocks x 32 batch rows, 49 steps ----
__global__ __launch_bounds__(512, 2) void gru_persistent(
    const int* __restrict__ toks, const float* __restrict__ tab,
    const short* __restrict__ Wh0, const short* __restrict__ Wi1, const short* __restrict__ Wh1,
    const float* __restrict__ bhh0, const float* __restrict__ bih1, const float* __restrict__ bhh1,
    const float* __restrict__ h0f, const float* __restrict__ h1f,
    short* __restrict__ Yb)
{
    __shared__ short h0L[32 * HPAD];
    __shared__ short h1L[32 * HPAD];
    __shared__ int tokL[32 * TTOT];

    const int tid = threadIdx.x;
    const int wave = tid >> 6, lane = tid & 63, quad = lane >> 4, l15 = lane & 15;
    const int rowbase = blockIdx.x * 32;

    // --- stage LDS h (bf16) + tokens ---
    for (int idx = tid; idx < 1024; idx += 512) {        // 32 rows * 32 chunks of 8
        int row = idx >> 5, col = (idx & 31) * 8;
        const float* s0 = h0f + (size_t)(rowbase + row) * HID + col;
        const float* s1 = h1f + (size_t)(rowbase + row) * HID + col;
        short t0[8], t1[8];
        #pragma unroll
        for (int j = 0; j < 8; ++j) { t0[j] = f2b(s0[j]); t1[j] = f2b(s1[j]); }
        *(bf16x8*)&h0L[row * HPAD + col] = *(bf16x8*)t0;
        *(bf16x8*)&h1L[row * HPAD + col] = *(bf16x8*)t1;
    }
    for (int idx = tid; idx < 32 * TTOT; idx += 512) {
        int row = idx / TTOT, tt = idx - row * TTOT;
        tokL[idx] = (tt == 0) ? START_TOK : toks[(size_t)(rowbase + row) * TTOT + tt];
    }

    // fp32 h carry in registers (C-layout: rows quad*4+r, col wave*32+c*16+l15)
    float h0r[2][2][4], h1r[2][2][4];
    #pragma unroll
    for (int i = 0; i < 2; ++i)
        #pragma unroll
        for (int c = 0; c < 2; ++c) {
            int col = wave * 32 + c * 16 + l15;
            #pragma unroll
            for (int r_ = 0; r_ < 4; ++r_) {
                int row = rowbase + 16 * i + quad * 4 + r_;
                h0r[i][c][r_] = h0f[(size_t)row * HID + col];
                h1r[i][c][r_] = h1f[(size_t)row * HID + col];
            }
        }
    __syncthreads();

    // per-wave packed-weight base pointers (j = gate*2 + half)
    const short* WA[6]; const short* WB[6]; const short* WC[6];
    #pragma unroll
    for (int g = 0; g < 3; ++g)
        #pragma unroll
        for (int c = 0; c < 2; ++c) {
            int nt = g * 16 + wave * 2 + c;      // global n-tile index
            WA[g * 2 + c] = Wh0 + (size_t)nt * 4096 + lane * 8;
            WB[g * 2 + c] = Wh1 + (size_t)nt * 4096 + lane * 8;
            WC[g * 2 + c] = Wi1 + (size_t)nt * 4096 + lane * 8;
        }

    const size_t mtg0 = (size_t)(rowbase >> 4);   // global 16-row tile base

    for (int t = 0; t < TS; ++t) {
        // ---- merged kloop: gh0 (h0 @ Wh0.T) and gh1 (h1 @ Wh1.T) ----
        f32x4 acc0[2][6] = {};
        f32x4 accrz[2][4] = {}, acchn[2][2] = {};
        #pragma unroll 2
        for (int kc = 0; kc < 8; ++kc) {
            bf16x8 a0[2], a1[2];
            #pragma unroll
            for (int i = 0; i < 2; ++i) {
                a0[i] = *(const bf16x8*)&h0L[(16 * i + l15) * HPAD + kc * 32 + quad * 8];
                a1[i] = *(const bf16x8*)&h1L[(16 * i + l15) * HPAD + kc * 32 + quad * 8];
            }
            #pragma unroll
            for (int j = 0; j < 6; ++j) {
                bf16x8 b0 = *(const bf16x8*)(WA[j] + kc * 512);
                #pragma unroll
                for (int i = 0; i < 2; ++i)
                    acc0[i][j] = __builtin_amdgcn_mfma_f32_16x16x32_bf16(a0[i], b0, acc0[i][j], 0, 0, 0);
            }
            #pragma unroll
            for (int j = 0; j < 6; ++j) {
                bf16x8 b1 = *(const bf16x8*)(WB[j] + kc * 512);
                #pragma unroll
                for (int i = 0; i < 2; ++i) {
                    if (j < 4) accrz[i][j] = __builtin_amdgcn_mfma_f32_16x16x32_bf16(a1[i], b1, accrz[i][j], 0, 0, 0);
                    else       acchn[i][j - 4] = __builtin_amdgcn_mfma_f32_16x16x32_bf16(a1[i], b1, acchn[i][j - 4], 0, 0, 0);
                }
            }
        }
        // ---- layer-0 gates (gi0 from fp32 token table) ----
        #pragma unroll
        for (int c = 0; c < 2; ++c) {
            int col = wave * 32 + c * 16 + l15;
            float br = bhh0[col], bz = bhh0[256 + col], bn = bhh0[512 + col];
            #pragma unroll
            for (int i = 0; i < 2; ++i)
                #pragma unroll
                for (int r_ = 0; r_ < 4; ++r_) {
                    int rl = 16 * i + quad * 4 + r_;
                    const float* tp = tab + (size_t)tokL[rl * TTOT + t] * N3 + col;
                    float r  = sigm(acc0[i][c][r_] + br + tp[0]);
                    float z  = sigm(acc0[i][2 + c][r_] + bz + tp[256]);
                    float n  = tanh_(tp[512] + r * (acc0[i][4 + c][r_] + bn));
                    h0r[i][c][r_] = (1.f - z) * n + z * h0r[i][c][r_];
                }
        }
        __syncthreads();   // all waves done reading h0L
        #pragma unroll
        for (int c = 0; c < 2; ++c) {
            int col = wave * 32 + c * 16 + l15;
            #pragma unroll
            for (int i = 0; i < 2; ++i)
                #pragma unroll
                for (int r_ = 0; r_ < 4; ++r_)
                    h0L[(16 * i + quad * 4 + r_) * HPAD + col] = f2b(h0r[i][c][r_]);
        }
        __syncthreads();   // h0n visible to all

        // ---- kloop gi1 = h0n @ Wi1.T (rz on top of gh1-rz, n separate) ----
        f32x4 accgn[2][2] = {};
        #pragma unroll 2
        for (int kc = 0; kc < 8; ++kc) {
            bf16x8 a[2];
            #pragma unroll
            for (int i = 0; i < 2; ++i)
                a[i] = *(const bf16x8*)&h0L[(16 * i + l15) * HPAD + kc * 32 + quad * 8];
            #pragma unroll
            for (int j = 0; j < 6; ++j) {
                bf16x8 b = *(const bf16x8*)(WC[j] + kc * 512);
                #pragma unroll
                for (int i = 0; i < 2; ++i) {
                    if (j < 4) accrz[i][j] = __builtin_amdgcn_mfma_f32_16x16x32_bf16(a[i], b, accrz[i][j], 0, 0, 0);
                    else       accgn[i][j - 4] = __builtin_amdgcn_mfma_f32_16x16x32_bf16(a[i], b, accgn[i][j - 4], 0, 0, 0);
                }
            }
        }
        // ---- layer-1 gates ----
        #pragma unroll
        for (int c = 0; c < 2; ++c) {
            int col = wave * 32 + c * 16 + l15;
            float brr = bih1[col] + bhh1[col];
            float brz = bih1[256 + col] + bhh1[256 + col];
            float bni = bih1[512 + col], bnh = bhh1[512 + col];
            #pragma unroll
            for (int i = 0; i < 2; ++i)
                #pragma unroll
                for (int r_ = 0; r_ < 4; ++r_) {
                    float r = sigm(accrz[i][c][r_] + brr);
                    float z = sigm(accrz[i][2 + c][r_] + brz);
                    float n = tanh_(accgn[i][c][r_] + bni + r * (acchn[i][c][r_] + bnh));
                    h1r[i][c][r_] = (1.f - z) * n + z * h1r[i][c][r_];
                }
        }
        __syncthreads();   // all waves done reading h1L
        #pragma unroll
        for (int c = 0; c < 2; ++c) {
            int col = wave * 32 + c * 16 + l15;
            #pragma unroll
            for (int i = 0; i < 2; ++i)
                #pragma unroll
                for (int r_ = 0; r_ < 4; ++r_)
                    h1L[(16 * i + quad * 4 + r_) * HPAD + col] = f2b(h1r[i][c][r_]);
        }
        __syncthreads();   // h1n visible

        // ---- packed Y[t] write (fragment order, coalesced 1KB stores) ----
        #pragma unroll
        for (int it = 0; it < 2; ++it) {
            int pair = wave + it * 8;            // 16 (mt,kc) pairs
            int mt = pair >> 3, kc = pair & 7;
            bf16x8 v = *(const bf16x8*)&h1L[(mt * 16 + l15) * HPAD + kc * 32 + quad * 8];
            *(bf16x8*)(Yb + ((((size_t)t * 512 + mtg0 + mt) * 8 + kc) << 9) + lane * 8) = v;
        }
        // no extra barrier: next h1L write is after the next gates1 barrier
    }
}

// ---- fused head: hdd = relu(Y@W1.T+b1) in LDS, logits = hdd@W2.T+b2 ----
__global__ __launch_bounds__(256) void head_kernel(
    const short* __restrict__ YP, const short* __restrict__ W1P, const float* __restrict__ b1,
    const short* __restrict__ W2P, const float* __restrict__ b2, float* __restrict__ out)
{
    __shared__ short hddL[64 * HPAD];
    int wave = threadIdx.x >> 6;
    int lane = threadIdx.x & 63;
    int quad = lane >> 4;
    int l15  = lane & 15;
    int rbase = blockIdx.x * 64;
    int tt = rbase >> 13;                 // time index (rows = t*8192 + b)
    int mb = (rbase & 8191) >> 4;         // 16-row tile base within t

    { // stage A: hdd tile 64x256; wave w owns n-tiles [w*4, w*4+4)
        const short* ybase = YP + ((size_t)tt * 512 + mb) * 4096 + lane * 8;
        const short* wbase = W1P + (size_t)(wave * 4) * 4096 + lane * 8;
        f32x4 acc[4][4] = {};
        #pragma unroll 2
        for (int kc = 0; kc < 8; ++kc) {
            bf16x8 a[4], bfr[4];
            #pragma unroll
            for (int i = 0; i < 4; ++i) a[i] = *(const bf16x8*)(ybase + (size_t)i * 4096 + kc * 512);
            #pragma unroll
            for (int j = 0; j < 4; ++j) bfr[j] = *(const bf16x8*)(wbase + (size_t)j * 4096 + kc * 512);
            #pragma unroll
            for (int i = 0; i < 4; ++i)
                #pragma unroll
                for (int j = 0; j < 4; ++j)
                    acc[i][j] = __builtin_amdgcn_mfma_f32_16x16x32_bf16(a[i], bfr[j], acc[i][j], 0, 0, 0);
        }
        #pragma unroll
        for (int i = 0; i < 4; ++i)
            #pragma unroll
            for (int j = 0; j < 4; ++j)
                #pragma unroll
                for (int r = 0; r < 4; ++r) {
                    int rl = i * 16 + quad * 4 + r;
                    int c  = wave * 64 + j * 16 + l15;
                    float v = acc[i][j][r] + b1[c];
                    hddL[rl * HPAD + c] = f2b(fmaxf(v, 0.f));
                }
    }
    __syncthreads();
    // stage B: 20 subtiles (10 col-tiles x 2 row-halves) / 4 waves
    for (int s = wave * 5; s < wave * 5 + 5; ++s) {
        int ct = s >> 1, rh = s & 1;
        const short* w2b = W2P + (size_t)ct * 4096 + lane * 8;
        f32x4 acc2[2] = {};
        #pragma unroll 2
        for (int kc = 0; kc < 8; ++kc) {
            bf16x8 bfr = *(const bf16x8*)(w2b + kc * 512);
            #pragma unroll
            for (int it = 0; it < 2; ++it) {
                bf16x8 a = *(const bf16x8*)&hddL[(rh * 32 + it * 16 + l15) * HPAD + kc * 32 + quad * 8];
                acc2[it] = __builtin_amdgcn_mfma_f32_16x16x32_bf16(a, bfr, acc2[it], 0, 0, 0);
            }
        }
        int col = ct * 16 + l15;
        if (col < VOCAB) {
            #pragma unroll
            for (int it = 0; it < 2; ++it)
                #pragma unroll
                for (int r = 0; r < 4; ++r) {
                    int rl = rh * 32 + it * 16 + quad * 4 + r;
                    int gr = rbase + rl;
                    int t2 = gr >> 13;
                    int bb = gr & 8191;
                    out[((size_t)bb * TS + t2) * VOCAB + col] = acc2[it][r] + b2[col];
                }
        }
    }
}

// ---- generated = target_tokens[:,1:] as float ----
__global__ __launch_bounds__(256) void gen_copy(const int* __restrict__ toks, float* __restrict__ out2)
{
    int tid = blockIdx.x * 256 + threadIdx.x;
    if (tid < BATCH * TS) {
        int b = tid / TS, j = tid - b * TS;
        out2[tid] = (float)toks[b * TTOT + j + 1];
    }
}

extern "C" void kernel_launch(void* const* d_in, const int* in_sizes, int n_in,
                              void* d_out, int out_size, void* d_ws, size_t ws_size,
                              hipStream_t stream) {
    const float* z     = (const float*)d_in[0];
    const int*   toks  = (const int*)d_in[1];
    const float* emb   = (const float*)d_in[2];
    const float* W_lat = (const float*)d_in[3];
    const float* b_lat = (const float*)d_in[4];
    const float* W_ih0 = (const float*)d_in[5];
    const float* W_hh0 = (const float*)d_in[6];
    const float* b_ih0 = (const float*)d_in[7];
    const float* b_hh0 = (const float*)d_in[8];
    const float* W_ih1 = (const float*)d_in[9];
    const float* W_hh1 = (const float*)d_in[10];
    const float* b_ih1 = (const float*)d_in[11];
    const float* b_hh1 = (const float*)d_in[12];
    const float* W1    = (const float*)d_in[13];
    const float* b1    = (const float*)d_in[14];
    const float* W2    = (const float*)d_in[15];
    const float* b2    = (const float*)d_in[16];

    char* w = (char*)d_ws;
    short* Yb   = (short*)(w + OFF_Y);
    short* Wh0b = (short*)(w + OFF_WH0B);
    short* Wi1b = (short*)(w + OFF_WI1B);
    short* Wh1b = (short*)(w + OFF_WH1B);
    short* W1b  = (short*)(w + OFF_W1B);
    short* W2b  = (short*)(w + OFF_W2B);
    float* tab  = (float*)(w + OFF_TAB);
    float* h0f  = (float*)(w + OFF_H0F);
    float* h1f  = (float*)(w + OFF_H1F);

    float* out_logits = (float*)d_out;
    float* out_gen    = out_logits + (size_t)BATCH * TS * VOCAB;

    convert_w<<<2720, 256, 0, stream>>>(W_hh0, W_ih1, W_hh1, W1, W2,
                                        Wh0b, Wi1b, Wh1b, W1b, W2b);
    build_tab<<<(VOCAB * N3 + 255) / 256, 256, 0, stream>>>(emb, W_ih0, b_ih0, tab);
    init_h<<<(BATCH * 512) / 256, 256, 0, stream>>>(z, W_lat, b_lat, h0f, h1f);
    gen_copy<<<(BATCH * TS + 255) / 256, 256, 0, stream>>>(toks, out_gen);

    gru_persistent<<<256, 512, 0, stream>>>(toks, tab, Wh0b, Wi1b, Wh1b,
                                            b_hh0, b_ih1, b_hh1, h0f, h1f, Yb);

    head_kernel<<<(BATCH * TS) / 64, 256, 0, stream>>>(Yb, W1b, b1, W2b, b2, out_logits);
}